// Round 1
// baseline (214.667 us; speedup 1.0000x reference)
//
#include <hip/hip_runtime.h>
#include <math.h>

#define BB 16
#define HH 256
#define WW 256
#define NPIX (BB*HH*WW)
#define BIGD 512.0f   // H + W

// ws layout (floats):
// [0, NPIX)        : d1sq flavor0 (mask)  -> overwritten with phi by rowmin
// [NPIX, 2*NPIX)   : d1sq flavor1 (1-mask)
// then: maxphi[16] (uint bits), anyflag[16] (int), accum[8] (float)

__global__ void init_kernel(unsigned* maxphi, int* anyflag, float* accum) {
    int t = threadIdx.x;
    if (t < 16) { maxphi[t] = 0u; anyflag[t] = 0; }
    if (t < 8)  accum[t] = 0.0f;
}

// One thread per (b, flavor, column). Down-scan stores raw distance; up-scan
// detects zeros via d==0, mins with below-distance, caps at BIG, squares.
__global__ void colscan_kernel(const float* __restrict__ targ,
                               float* __restrict__ d1,
                               int* __restrict__ anyflag) {
    int tid = blockIdx.x * blockDim.x + threadIdx.x;   // [0, BB*2*WW)
    int j = tid & (WW - 1);
    int f = (tid >> 8) & 1;
    int b = tid >> 9;
    const float* m = targ + b * HH * WW + j;
    float* o = d1 + f * NPIX + b * HH * WW + j;

    int last = -1;
    int any = 0;
    #pragma unroll 8
    for (int i = 0; i < HH; ++i) {
        float mv = m[i * WW];
        bool z = (f == 0) ? (mv == 0.0f) : (mv != 0.0f);
        any |= (mv != 0.0f);
        if (z) last = i;
        float d = (last < 0) ? BIGD : (float)(i - last);
        o[i * WW] = d;
    }
    if (f == 0 && any) atomicOr(&anyflag[b], 1);

    last = -1;
    #pragma unroll 8
    for (int i = HH - 1; i >= 0; --i) {
        float d = o[i * WW];
        if (d == 0.0f) last = i;
        if (last >= 0) d = fminf(d, (float)(last - i));
        d = fminf(d, BIGD);
        o[i * WW] = d * d;
    }
}

// One block per (b, row). d1sq rows staged in LDS (broadcast reads).
// phi overwrites the flavor-0 row in place. Per-image max|phi| via atomicMax.
__global__ __launch_bounds__(256) void rowmin_kernel(float* __restrict__ d1,
                                                     const int* __restrict__ anyflag,
                                                     unsigned* __restrict__ maxphi) {
    int bi = blockIdx.x;            // b*HH + i
    int b = bi >> 8;
    int j = threadIdx.x;
    __shared__ float sin_[WW];
    __shared__ float sout_[WW];
    float* rowin = d1 + bi * WW;                 // flavor0 (dist_inside)
    const float* rowout = d1 + NPIX + bi * WW;   // flavor1 (dist_outside)
    sin_[j]  = rowin[j];
    sout_[j] = rowout[j];
    __syncthreads();

    float bin = 1e30f, bout = 1e30f;
    #pragma unroll 8
    for (int k = 0; k < WW; ++k) {
        float dj = (float)(j - k);
        float o2 = dj * dj;
        bin  = fminf(bin,  sin_[k]  + o2);
        bout = fminf(bout, sout_[k] + o2);
    }
    float phi = sqrtf(bout) - sqrtf(bin);
    if (anyflag[b] == 0) phi = 0.0f;
    rowin[j] = phi;

    float a = fabsf(phi);
    #pragma unroll
    for (int off = 32; off > 0; off >>= 1)
        a = fmaxf(a, __shfl_down(a, off, 64));
    __shared__ float wmax[4];
    int lane = j & 63, wv = j >> 6;
    if (lane == 0) wmax[wv] = a;
    __syncthreads();
    if (j == 0) {
        float mx = fmaxf(fmaxf(wmax[0], wmax[1]), fmaxf(wmax[2], wmax[3]));
        atomicMax(&maxphi[b], __float_as_uint(mx));
    }
}

// Fused: sigmoid, dice partial sums, BCE, normalized-phi dot probs.
__global__ __launch_bounds__(256) void reduce_kernel(const float* __restrict__ pred,
                                                     const float* __restrict__ targ,
                                                     const float* __restrict__ phi,
                                                     const unsigned* __restrict__ maxphi,
                                                     float* __restrict__ accum) {
    int idx0 = blockIdx.x * blockDim.x + threadIdx.x;
    int stride = gridDim.x * blockDim.x;
    float sp = 0.f, st = 0.f, spt = 0.f, sbce = 0.f, sbnd = 0.f;
    for (int idx = idx0; idx < NPIX; idx += stride) {
        float x = pred[idx];
        float t = targ[idx];
        float p = 1.0f / (1.0f + expf(-x));
        sp  += p;
        st  += t;
        spt += p * t;
        sbce += fmaxf(x, 0.0f) - x * t + log1pf(expf(-fabsf(x)));
        int b = idx >> 16;   // HH*WW = 65536
        float denom = __uint_as_float(maxphi[b]) + 1e-8f;
        sbnd += (phi[idx] / denom) * p;
    }
    // wave reduce all 5
    #pragma unroll
    for (int off = 32; off > 0; off >>= 1) {
        sp   += __shfl_down(sp,   off, 64);
        st   += __shfl_down(st,   off, 64);
        spt  += __shfl_down(spt,  off, 64);
        sbce += __shfl_down(sbce, off, 64);
        sbnd += __shfl_down(sbnd, off, 64);
    }
    __shared__ float ws[4][5];
    int lane = threadIdx.x & 63, wv = threadIdx.x >> 6;
    if (lane == 0) { ws[wv][0]=sp; ws[wv][1]=st; ws[wv][2]=spt; ws[wv][3]=sbce; ws[wv][4]=sbnd; }
    __syncthreads();
    if (threadIdx.x < 5) {
        float v = ws[0][threadIdx.x] + ws[1][threadIdx.x] + ws[2][threadIdx.x] + ws[3][threadIdx.x];
        atomicAdd(&accum[threadIdx.x], v);
    }
}

__global__ void final_kernel(const float* __restrict__ accum, float* __restrict__ out) {
    float sp = accum[0], st = accum[1], spt = accum[2], sbce = accum[3], sbnd = accum[4];
    float dice = 1.0f - (2.0f * spt + 1e-6f) / (sp + st + 1e-6f);
    float invN = 1.0f / (float)NPIX;
    float boundary = sbnd * invN;
    float bce = sbce * invN;
    float alpha = 0.005f;
    float beta = 0.6f - alpha;          // 0.595
    out[0] = (1.0f - beta) * dice + beta * boundary + 0.4f * bce;
}

extern "C" void kernel_launch(void* const* d_in, const int* in_sizes, int n_in,
                              void* d_out, int out_size, void* d_ws, size_t ws_size,
                              hipStream_t stream) {
    (void)in_sizes; (void)n_in; (void)out_size; (void)ws_size;
    const float* pred = (const float*)d_in[0];
    const float* targ = (const float*)d_in[1];
    float* ws = (float*)d_ws;
    float* d1 = ws;                                   // 2*NPIX floats
    unsigned* maxphi = (unsigned*)(ws + 2 * NPIX);    // 16
    int* anyflag = (int*)(maxphi + 16);               // 16
    float* accum = (float*)(anyflag + 16);            // 8

    init_kernel<<<1, 64, 0, stream>>>(maxphi, anyflag, accum);
    colscan_kernel<<<(BB * 2 * WW) / 256, 256, 0, stream>>>(targ, d1, anyflag);
    rowmin_kernel<<<BB * HH, 256, 0, stream>>>(d1, anyflag, maxphi);
    reduce_kernel<<<1024, 256, 0, stream>>>(pred, targ, d1, maxphi, accum);
    final_kernel<<<1, 1, 0, stream>>>(accum, (float*)d_out);
}